// Round 1
// baseline (98.487 us; speedup 1.0000x reference)
//
#include <hip/hip_runtime.h>

#define NPOS 1024
#define D 8

// ws layout (floats): [0..7]=w1, [8..71]=W2 (row-major 8x8), [72]=d, [73]=c
__global__ void sig_prep(const float* __restrict__ W_sig, const float* __restrict__ b_sig,
                         const float* __restrict__ W_v,  const float* __restrict__ b_v,
                         const float* __restrict__ W_o,  const float* __restrict__ b_o,
                         const float* __restrict__ W_out,const float* __restrict__ b_out,
                         float* __restrict__ ws) {
    __shared__ float u1[64];
    __shared__ float u[64];
    const int tid = threadIdx.x;
    if (tid < 64) {
        float s = 0.f;
        for (int j = 0; j < 64; ++j) s += W_o[tid * 64 + j] * W_out[j];
        u1[tid] = s;
    }
    __syncthreads();
    if (tid < 64) {
        float s = 0.f;
        for (int j = 0; j < 64; ++j) s += W_v[tid * 64 + j] * u1[j];
        u[tid] = s;
    }
    __syncthreads();
    if (tid < 72) {
        float s = 0.f;
        for (int j = 0; j < 64; ++j) s += W_sig[tid * 64 + j] * u[j];
        ws[tid] = s;
    }
    if (tid == 72) {
        float c = b_out[0];
        for (int j = 0; j < 64; ++j) c += b_v[j] * u1[j] + b_o[j] * W_out[j];
        float dd = c;
        for (int j = 0; j < 64; ++j) dd += b_sig[j] * u[j];
        ws[72] = dd;
        ws[73] = c;
    }
}

__global__ __launch_bounds__(256) void sig_main(const float* __restrict__ feat,
                                                const float* __restrict__ ws,
                                                float* __restrict__ out) {
    __shared__ float w2s[64];
    __shared__ float w1s[8];
    __shared__ float wtot[4];

    const int tid = threadIdx.x;
    const int b   = blockIdx.x;

    if (tid < 64) w2s[tid] = ws[8 + tid];
    else if (tid < 72) w1s[tid - 64] = ws[tid - 64];
    const float dval = ws[72];
    const float cval = ws[73];

    const float* __restrict__ frow = feat + (size_t)b * NPOS * D;

    // f0 (broadcast load, L1-cached)
    float f0[D];
    {
        float4 a0 = *reinterpret_cast<const float4*>(frow);
        float4 a1 = *reinterpret_cast<const float4*>(frow + 4);
        f0[0]=a0.x; f0[1]=a0.y; f0[2]=a0.z; f0[3]=a0.w;
        f0[4]=a1.x; f0[5]=a1.y; f0[6]=a1.z; f0[7]=a1.w;
    }

    const int a = tid * 4;            // this thread's g-chunk: s in [a, a+4)
    float fp[D];
    {
        float4 p0 = *reinterpret_cast<const float4*>(frow + a * D);
        float4 p1 = *reinterpret_cast<const float4*>(frow + a * D + 4);
        fp[0]=p0.x; fp[1]=p0.y; fp[2]=p0.z; fp[3]=p0.w;
        fp[4]=p1.x; fp[5]=p1.y; fp[6]=p1.z; fp[7]=p1.w;
    }

    __syncthreads();   // w2s/w1s visible

    float l[4];        // local inclusive prefix of g
    float dotv[4];     // (f[s+1]-f0).w1 per position
    float run = 0.f;
#pragma unroll
    for (int i = 0; i < 4; ++i) {
        const int s = a + i;
        float gi = 0.f;
        if (s < NPOS - 1) {
            float fn[D];
            float4 n0 = *reinterpret_cast<const float4*>(frow + (s + 1) * D);
            float4 n1 = *reinterpret_cast<const float4*>(frow + (s + 1) * D + 4);
            fn[0]=n0.x; fn[1]=n0.y; fn[2]=n0.z; fn[3]=n0.w;
            fn[4]=n1.x; fn[5]=n1.y; fn[6]=n1.z; fn[7]=n1.w;

            float inc[D];
#pragma unroll
            for (int k = 0; k < D; ++k) inc[k] = fn[k] - fp[k];
#pragma unroll
            for (int r = 0; r < D; ++r) {
                float acc = 0.f;
#pragma unroll
                for (int j = 0; j < D; ++j) acc += w2s[r * D + j] * inc[j];
                gi += (fp[r] - f0[r]) * acc;
            }
            float dv = 0.f;
#pragma unroll
            for (int k = 0; k < D; ++k) dv += (fn[k] - f0[k]) * w1s[k];
            dotv[i] = dv;
#pragma unroll
            for (int k = 0; k < D; ++k) fp[k] = fn[k];
        } else {
            dotv[i] = 0.f;
        }
        run += gi;
        l[i] = run;
    }

    // inclusive wave scan of per-thread totals
    const int lane = tid & 63;
    const int wave = tid >> 6;
    float t = run;
#pragma unroll
    for (int off = 1; off < 64; off <<= 1) {
        float nv = __shfl_up(t, off);
        if (lane >= off) t += nv;
    }
    if (lane == 63) wtot[wave] = t;
    __syncthreads();
    float base = t - run;              // exclusive within wave
#pragma unroll
    for (int w = 0; w < 4; ++w)
        if (w < wave) base += wtot[w];

    float* __restrict__ orow = out + (size_t)b * NPOS;
    if (tid == 0) orow[0] = cval;
#pragma unroll
    for (int i = 0; i < 4; ++i) {
        const int s = a + i;
        const int tpos = s + 1;        // delta[t] uses G[t-1]
        if (tpos < NPOS) {
            orow[tpos] = dotv[i] + base + l[i] + dval;
        }
    }
}

extern "C" void kernel_launch(void* const* d_in, const int* in_sizes, int n_in,
                              void* d_out, int out_size, void* d_ws, size_t ws_size,
                              hipStream_t stream) {
    const float* features = (const float*)d_in[0];
    const float* W_sig    = (const float*)d_in[1];
    const float* b_sig    = (const float*)d_in[2];
    // d_in[3..8] = W_feat, b_feat, W_q, b_q, W_k, b_k  -- dead code (softmax over one key == 1)
    const float* W_v      = (const float*)d_in[9];
    const float* b_v      = (const float*)d_in[10];
    const float* W_o      = (const float*)d_in[11];
    const float* b_o      = (const float*)d_in[12];
    const float* W_out    = (const float*)d_in[13];
    const float* b_out    = (const float*)d_in[14];

    float* ws  = (float*)d_ws;
    float* out = (float*)d_out;

    sig_prep<<<1, 128, 0, stream>>>(W_sig, b_sig, W_v, b_v, W_o, b_o, W_out, b_out, ws);
    sig_main<<<512, 256, 0, stream>>>(features, ws, out);
}

// Round 2
// 96.720 us; speedup vs baseline: 1.0183x; 1.0183x over previous
//
#include <hip/hip_runtime.h>

#define NPOS 1024
#define D 8

// One block per batch row; 1024 threads, one sequence position per thread.
// Each block redundantly folds the affine weight chain (tiny, L2-resident),
// then computes g[s] = (f[s]-f0)^T W2 (f[s+1]-f[s]) and an inclusive scan.
__global__ __launch_bounds__(1024) void sig_fused(
    const float* __restrict__ feat,
    const float* __restrict__ W_sig, const float* __restrict__ b_sig,
    const float* __restrict__ W_v,   const float* __restrict__ b_v,
    const float* __restrict__ W_o,   const float* __restrict__ b_o,
    const float* __restrict__ W_out, const float* __restrict__ b_out,
    float* __restrict__ out)
{
    __shared__ float u1[64];     // W_o @ W_out
    __shared__ float uu[64];     // W_v @ u1
    __shared__ float w2s[64];    // rows 8..71 of W_sig @ uu  (8x8)
    __shared__ float w1s[8];     // rows 0..7  of W_sig @ uu
    __shared__ float dc[2];      // dc[0]=d (full bias term), dc[1]=c (t=0 value)
    __shared__ float wtot[16];   // per-wave scan totals

    const int tid = threadIdx.x;
    const int b   = blockIdx.x;
    const float* __restrict__ frow = feat + (size_t)b * NPOS * D;

    // ---- issue feature loads first (in flight during the weight fold) ----
    float fs[D], fn[D], f0[D];
    {
        float4 a0 = *reinterpret_cast<const float4*>(frow + tid * D);
        float4 a1 = *reinterpret_cast<const float4*>(frow + tid * D + 4);
        fs[0]=a0.x; fs[1]=a0.y; fs[2]=a0.z; fs[3]=a0.w;
        fs[4]=a1.x; fs[5]=a1.y; fs[6]=a1.z; fs[7]=a1.w;
    }
    {
        const int sn = (tid < NPOS - 1) ? (tid + 1) : tid;   // clamp (unused when clamped)
        float4 a0 = *reinterpret_cast<const float4*>(frow + sn * D);
        float4 a1 = *reinterpret_cast<const float4*>(frow + sn * D + 4);
        fn[0]=a0.x; fn[1]=a0.y; fn[2]=a0.z; fn[3]=a0.w;
        fn[4]=a1.x; fn[5]=a1.y; fn[6]=a1.z; fn[7]=a1.w;
    }
    {
        float4 a0 = *reinterpret_cast<const float4*>(frow);
        float4 a1 = *reinterpret_cast<const float4*>(frow + 4);
        f0[0]=a0.x; f0[1]=a0.y; f0[2]=a0.z; f0[3]=a0.w;
        f0[4]=a1.x; f0[5]=a1.y; f0[6]=a1.z; f0[7]=a1.w;
    }

    // ---- weight fold (redundant per block; weights are L1/L2 resident) ----
    if (tid < 64) {
        float s = 0.f;
#pragma unroll
        for (int j = 0; j < 64; ++j) s += W_o[tid * 64 + j] * W_out[j];
        u1[tid] = s;
    }
    __syncthreads();
    if (tid < 64) {
        float s = 0.f;
#pragma unroll
        for (int j = 0; j < 64; ++j) s += W_v[tid * 64 + j] * u1[j];
        uu[tid] = s;
    } else if (tid == 64) {
        float c = b_out[0];
#pragma unroll
        for (int j = 0; j < 64; ++j) c += b_v[j] * u1[j] + b_o[j] * W_out[j];
        dc[1] = c;
    }
    __syncthreads();
    if (tid < 72) {
        float s = 0.f;
#pragma unroll
        for (int j = 0; j < 64; ++j) s += W_sig[tid * 64 + j] * uu[j];
        if (tid < 8) w1s[tid] = s;
        else         w2s[tid - 8] = s;
    } else if (tid == 72) {
        float dd = dc[1];
#pragma unroll
        for (int j = 0; j < 64; ++j) dd += b_sig[j] * uu[j];
        dc[0] = dd;
    }
    __syncthreads();

    // ---- per-position term ----
    float gi = 0.f, dv = 0.f;
    if (tid < NPOS - 1) {
        float inc[D];
#pragma unroll
        for (int k = 0; k < D; ++k) inc[k] = fn[k] - fs[k];
#pragma unroll
        for (int r = 0; r < D; ++r) {
            float acc = 0.f;
#pragma unroll
            for (int j = 0; j < D; ++j) acc += w2s[r * D + j] * inc[j];
            gi += (fs[r] - f0[r]) * acc;
        }
#pragma unroll
        for (int k = 0; k < D; ++k) dv += (fn[k] - f0[k]) * w1s[k];
    }

    // ---- inclusive scan of gi across 1024 threads ----
    const int lane = tid & 63;
    const int wave = tid >> 6;
    float t = gi;
#pragma unroll
    for (int off = 1; off < 64; off <<= 1) {
        float nv = __shfl_up(t, off);
        if (lane >= off) t += nv;
    }
    if (lane == 63) wtot[wave] = t;
    __syncthreads();
    float base = 0.f;
#pragma unroll
    for (int w = 0; w < 16; ++w)
        if (w < wave) base += wtot[w];

    // ---- write ----
    float* __restrict__ orow = out + (size_t)b * NPOS;
    if (tid == 0) orow[0] = dc[1];
    if (tid < NPOS - 1) orow[tid + 1] = dv + base + t + dc[0];
}

extern "C" void kernel_launch(void* const* d_in, const int* in_sizes, int n_in,
                              void* d_out, int out_size, void* d_ws, size_t ws_size,
                              hipStream_t stream) {
    const float* features = (const float*)d_in[0];
    const float* W_sig    = (const float*)d_in[1];
    const float* b_sig    = (const float*)d_in[2];
    // d_in[3..8] = W_feat, b_feat, W_q, b_q, W_k, b_k  -- dead (softmax over one key == 1)
    const float* W_v      = (const float*)d_in[9];
    const float* b_v      = (const float*)d_in[10];
    const float* W_o      = (const float*)d_in[11];
    const float* b_o      = (const float*)d_in[12];
    const float* W_out    = (const float*)d_in[13];
    const float* b_out    = (const float*)d_in[14];

    float* o = (float*)d_out;
    sig_fused<<<512, 1024, 0, stream>>>(features, W_sig, b_sig, W_v, b_v,
                                        W_o, b_o, W_out, b_out, o);
}